// Round 18
// baseline (282.704 us; speedup 1.0000x reference)
//
#include <hip/hip_runtime.h>
#include <hip/hip_bf16.h>
#include <math.h>

#define D 256
#define INV_TAU 20.0f
#define CAP 64
#define PBUF 128
// fp8 inputs scaled by 16: acc = 256*sim. s = acc*INV_TAU/256.
#define ACC2S (INV_TAU / 256.0f)
#define K2F (ACC2S * 1.4426950408889634f)

typedef __attribute__((ext_vector_type(4))) float f32x4;

#define GLOAD16(gp, lp) \
    __builtin_amdgcn_global_load_lds((const __attribute__((address_space(1))) void*)(gp), \
                                     (__attribute__((address_space(3))) void*)(lp), 16, 0, 0)

// Wave per row: L2-normalize a 256-dim f32 row, scale by 16, emit fp8 e4m3 in
// PERMUTED layout: each 64B K-block stores 8B granules in order [0,4,1,5,2,6,3,7],
// so 16B position g holds lane-g's MFMA operands for the block's (kk-even, kk-odd)
// pair — one ds_read_b128 serves two K=32 MFMA steps (R16-verified, absmax 0.0).
__global__ void norm_all(const float* __restrict__ que, const float* __restrict__ sen,
                         const float* __restrict__ sec,
                         unsigned char* __restrict__ queb, unsigned char* __restrict__ senb,
                         unsigned char* __restrict__ secb, int Q, int N, int S) {
    int r = blockIdx.x * 4 + (threadIdx.x >> 6);
    int lane = threadIdx.x & 63;
    if (r >= Q + N + S) return;
    const float* src; unsigned char* dst; int row;
    if (r < Q) { src = que; dst = queb; row = r; }
    else if (r < Q + N) { src = sen; dst = senb; row = r - Q; }
    else { src = sec; dst = secb; row = r - Q - N; }
    const float4* p = (const float4*)(src + (size_t)row * D);
    float4 v = p[lane];
    float ss = v.x * v.x + v.y * v.y + v.z * v.z + v.w * v.w;
    #pragma unroll
    for (int m = 1; m < 64; m <<= 1) ss += __shfl_xor(ss, m);
    float s = rsqrtf(ss) * 16.0f;
    int pk = __builtin_amdgcn_cvt_pk_fp8_f32(v.x * s, v.y * s, 0, false);
    pk = __builtin_amdgcn_cvt_pk_fp8_f32(v.z * s, v.w * s, pk, true);
    // lane covers granule (lane>>1), half (lane&1); block = lane>>4, wg = (lane>>1)&7.
    int wg = (lane >> 1) & 7;
    int pos = (wg < 4) ? (2 * wg) : (2 * (wg - 4) + 1);
    int byte = ((lane >> 4) << 6) + (pos << 3) + ((lane & 1) << 2);
    *(int*)(dst + (size_t)row * D + byte) = pk;
}

// Mega kernel, 1-D grid = 32 SQ blocks + 4096 QS blocks, 256 threads.
// QS: m97-shape fp8 GEMM — 128x128 tile, BK=64 (one permuted 64B block/step),
// single LDS buffer, plain __syncthreads. Chunk swizzle c ^= (row>>1)&3 on
// SOURCE + READ, LDS linear (rule #21). Fragment = ONE ds_read_b128 per (r, two
// kk-steps): byte = r*64 + (g^((r>>1)&3))*16 — R6/R16's measured-0-conflict pattern.
// launch_bounds(256,8): VGPR=64 & LDS=19.5KB both allow 8 blocks/CU — request it.
__global__ __launch_bounds__(256, 8)
void qs_sq(const unsigned char* __restrict__ queb, const unsigned char* __restrict__ senb,
           const unsigned char* __restrict__ secb,
           const int* __restrict__ pidq, const int* __restrict__ pidn,
           const int* __restrict__ sidx, int Q,
           float* __restrict__ partial, int* __restrict__ cnt, float* __restrict__ pos_s,
           float* __restrict__ sq_all, float* __restrict__ sq_pos, int* __restrict__ sq_m,
           float* __restrict__ simq) {
    __shared__ unsigned char As[128 * 64];
    __shared__ unsigned char Bs[128 * 64];
    __shared__ int pqs[128];
    __shared__ int pns[128];
    __shared__ float sums[2][128];
    __shared__ int lcnt;
    __shared__ int lq[PBUF];
    __shared__ float lsv[PBUF];

    const int tid = threadIdx.x;
    const int lane = tid & 63;
    const int cl = lane & 15;
    const int g = lane >> 4;
    const int wid = tid >> 6;
    const int bid = blockIdx.x;
    const int nsq = Q >> 7;   // 32 SQ blocks

    if (bid < nsq) {
        // ---------------- SQ path: 64 sections x 128 questions (fp8, permuted) ----------------
        const int q0 = bid * 128;
        const int qw = q0 + wid * 32;
        f32x4 acc[4][2];
        #pragma unroll
        for (int si = 0; si < 4; ++si)
            #pragma unroll
            for (int qi = 0; qi < 2; ++qi)
                acc[si][qi] = (f32x4){0.f, 0.f, 0.f, 0.f};
        const unsigned char* abase = secb + (size_t)cl * D + g * 16;
        const unsigned char* bbase = queb + (size_t)(qw + cl) * D + g * 16;
        #pragma unroll
        for (int b = 0; b < 4; ++b) {
            const int k0 = b * 64;
            long2 af[4], bq[2];
            #pragma unroll
            for (int si = 0; si < 4; ++si)
                af[si] = *(const long2*)(abase + (size_t)si * 16 * D + k0);
            #pragma unroll
            for (int qi = 0; qi < 2; ++qi)
                bq[qi] = *(const long2*)(bbase + (size_t)qi * 16 * D + k0);
            #pragma unroll
            for (int si = 0; si < 4; ++si)
                #pragma unroll
                for (int qi = 0; qi < 2; ++qi) {
                    acc[si][qi] = __builtin_amdgcn_mfma_f32_16x16x32_fp8_fp8(af[si].x, bq[qi].x, acc[si][qi], 0, 0, 0);
                    acc[si][qi] = __builtin_amdgcn_mfma_f32_16x16x32_fp8_fp8(af[si].y, bq[qi].y, acc[si][qi], 0, 0, 0);
                }
        }
        int sidxv[2];
        sidxv[0] = sidx[qw + cl];
        sidxv[1] = sidx[qw + 16 + cl];
        #pragma unroll
        for (int si = 0; si < 4; ++si) {
            float pa[4] = {0.f, 0.f, 0.f, 0.f};
            #pragma unroll
            for (int qi = 0; qi < 2; ++qi) {
                #pragma unroll
                for (int j = 0; j < 4; ++j) {
                    int srow = si * 16 + g * 4 + j;
                    float sv = acc[si][qi][j] * ACC2S;
                    float e = __expf(sv);
                    pa[j] += e;
                    if (sidxv[qi] == srow) {
                        int q = qw + qi * 16 + cl;
                        simq[q] = sv;
                        atomicAdd(&sq_pos[srow], e);
                        atomicAdd(&sq_m[srow], 1);
                    }
                }
            }
            #pragma unroll
            for (int j = 0; j < 4; ++j) {
                float a = pa[j];
                #pragma unroll
                for (int msk = 1; msk < 16; msk <<= 1) a += __shfl_xor(a, msk);
                if (cl == 0) atomicAdd(&sq_all[si * 16 + g * 4 + j], a);
            }
        }
        return;
    }

    // ---------------- QS path ----------------
    const int qbid = bid - nsq;
    const int qt = qbid & 31;       // 32 consecutive blocks share the same n-tile
    const int nt = qbid >> 5;       // 128 n-tiles
    const int wr = wid >> 1, wc = wid & 1;
    const int q0 = qt * 128;
    const int n0 = nt * 128;

    if (tid < 128) pqs[tid] = pidq[q0 + tid];
    else           pns[tid - 128] = pidn[n0 + tid - 128];
    if (tid == 0) lcnt = 0;

    // Staging: per K-step stage one 64B block: 128 rows x 4 chunks = 512 chunks
    // per matrix; thread covers cid = {tid, 256+tid}: row = cid>>2, c = cid&3.
    // Source chunk = c ^ ((row>>1)&3), LDS dest linear in cid.
    const int r0s = tid >> 2;             // rows 0..63
    const int c0s = tid & 3;
    const unsigned char* qa0 = queb + (size_t)(q0 + r0s) * D + ((c0s ^ ((r0s >> 1) & 3)) << 4);
    const unsigned char* qa1 = queb + (size_t)(q0 + 64 + r0s) * D + ((c0s ^ (((r0s + 64) >> 1) & 3)) << 4);
    const unsigned char* sb0 = senb + (size_t)(n0 + r0s) * D + ((c0s ^ ((r0s >> 1) & 3)) << 4);
    const unsigned char* sb1 = senb + (size_t)(n0 + 64 + r0s) * D + ((c0s ^ (((r0s + 64) >> 1) & 3)) << 4);
    const int ld0 = wid * 1024;           // byte base, chunks 0..255
    const int ld1 = 4096 + wid * 1024;    // chunks 256..511

#define STAGE(k0) do { \
    GLOAD16(qa0 + (k0), &As[ld0]); \
    GLOAD16(qa1 + (k0), &As[ld1]); \
    GLOAD16(sb0 + (k0), &Bs[ld0]); \
    GLOAD16(sb1 + (k0), &Bs[ld1]); \
} while (0)

    f32x4 acc[4][4];
    #pragma unroll
    for (int m = 0; m < 4; ++m)
        #pragma unroll
        for (int n = 0; n < 4; ++n)
            acc[m][n] = (f32x4){0.f, 0.f, 0.f, 0.f};

    // Fragment byte offsets: want global chunk (r, g); stored chunk = g ^ ((r>>1)&3),
    // and (r>>1)&3 == (cl>>1)&3 for all fragment rows (bases are multiples of 16).
    // One b128 per (frag row): lo 8B = kk-even operand, hi 8B = kk-odd operand.
    const int fsw = (g ^ ((cl >> 1) & 3)) << 4;
    int offA[4], offB[4];
    #pragma unroll
    for (int m = 0; m < 4; ++m) offA[m] = (wr * 64 + m * 16 + cl) * 64 + fsw;
    #pragma unroll
    for (int n = 0; n < 4; ++n) offB[n] = (wc * 64 + n * 16 + cl) * 64 + fsw;

    STAGE(0);
    #pragma unroll
    for (int ks = 0; ks < 4; ++ks) {
        __syncthreads();   // drains own vmcnt + rendezvous: LDS tile ready
        long2 af[4], bg[4];
        #pragma unroll
        for (int m = 0; m < 4; ++m) af[m] = *(const long2*)&As[offA[m]];
        #pragma unroll
        for (int n = 0; n < 4; ++n) bg[n] = *(const long2*)&Bs[offB[n]];
        #pragma unroll
        for (int m = 0; m < 4; ++m)
            #pragma unroll
            for (int n = 0; n < 4; ++n)
                acc[m][n] = __builtin_amdgcn_mfma_f32_16x16x32_fp8_fp8(af[m].x, bg[n].x, acc[m][n], 0, 0, 0);
        #pragma unroll
        for (int m = 0; m < 4; ++m)
            #pragma unroll
            for (int n = 0; n < 4; ++n)
                acc[m][n] = __builtin_amdgcn_mfma_f32_16x16x32_fp8_fp8(af[m].y, bg[n].y, acc[m][n], 0, 0, 0);
        if (ks < 3) {
            __syncthreads();          // all reads done before overwrite
            STAGE((ks + 1) * 64);
        }
    }
#undef STAGE

    // Epilogue: exp2 + per-row sums (block-local) + LDS positive capture.
    #pragma unroll
    for (int m = 0; m < 4; ++m) {
        float se[4] = {0.f, 0.f, 0.f, 0.f};
        int pqr[4];
        #pragma unroll
        for (int j = 0; j < 4; ++j) pqr[j] = pqs[wr * 64 + m * 16 + g * 4 + j];
        #pragma unroll
        for (int n = 0; n < 4; ++n) {
            const int pcol = pns[wc * 64 + n * 16 + cl];
            #pragma unroll
            for (int j = 0; j < 4; ++j) {
                float e = __builtin_amdgcn_exp2f(acc[m][n][j] * K2F);
                se[j] += e;
                if (pqr[j] == pcol) {
                    int li = atomicAdd(&lcnt, 1);
                    if (li < PBUF) {
                        lq[li] = q0 + wr * 64 + m * 16 + g * 4 + j;
                        lsv[li] = acc[m][n][j] * ACC2S;
                    }
                }
            }
        }
        #pragma unroll
        for (int j = 0; j < 4; ++j) {
            float a = se[j];
            #pragma unroll
            for (int msk = 1; msk < 16; msk <<= 1) a += __shfl_xor(a, msk);
            if (cl == 0) sums[wc][wr * 64 + m * 16 + g * 4 + j] = a;
        }
    }
    __syncthreads();
    if (tid < 128)
        partial[(size_t)nt * Q + q0 + tid] = sums[0][tid] + sums[1][tid];
    int nc = lcnt < PBUF ? lcnt : PBUF;
    for (int i = tid; i < nc; i += 256) {
        int q = lq[i];
        int idx = atomicAdd(&cnt[q], 1);
        if (idx < CAP) pos_s[(size_t)q * CAP + idx] = lsv[i];
    }
}

// Finish: wave per question. Reduces row partials, computes g + QS terms + SQ term.
__global__ __launch_bounds__(256)
void finish(const float* __restrict__ partial, int NSLICE,
            const int* __restrict__ cnt, const float* __restrict__ pos_s,
            const int* __restrict__ sidx, const float* __restrict__ simq,
            const float* __restrict__ sq_all, const float* __restrict__ sq_pos,
            const int* __restrict__ sq_m,
            const int* __restrict__ npp, int Qn, int Ntot,
            float* __restrict__ bpart) {
    __shared__ float fred[4][4];
    const int tid = threadIdx.x, lane = tid & 63, wid = tid >> 6;
    const int q = blockIdx.x * 4 + wid;

    float Sa = 0.f;
    for (int nb = lane; nb < NSLICE; nb += 64) Sa += partial[(size_t)nb * Qn + q];
    #pragma unroll
    for (int m = 1; m < 64; m <<= 1) Sa += __shfl_xor(Sa, m);

    int M = cnt[q];
    int mc = M < CAP ? M : CAP;
    float s = 0.f, e = 0.f;
    if (lane < mc) { s = pos_s[(size_t)q * CAP + lane]; e = __expf(s); }
    float Sp = e;
    #pragma unroll
    for (int m = 1; m < 64; m <<= 1) Sp += __shfl_xor(Sp, m);

    int Nn = Ntot - M;
    int P = npp[0];
    float eta_p = 1.0f / (float)(P > 1 ? P : 1);
    float eta_m = 1.0f - eta_p;
    float Mf = (float)(M > 1 ? M : 1);
    float Nnf = (float)(Nn > 1 ? Nn : 1);
    float gg = fmaxf(((Sa - Sp) / Nnf - eta_p * Sp / Mf) / eta_m, __expf(-INV_TAU));
    float c = (float)Nn * gg;

    float contrib = (lane < mc) ? (s - __logf(e + c)) : 0.f;
    #pragma unroll
    for (int m = 1; m < 64; m <<= 1) contrib += __shfl_xor(contrib, m);

    if (lane == 0) {
        float qs_num = 0.f, qs_cnt = 0.f, sq_num = 0.f, sq_cnt = 0.f;
        if (M > 0 && Nn > 0) { qs_num = contrib; qs_cnt = (float)M; }
        int sct = sidx[q];
        int Mq = sq_m[sct];
        if (Mq > 0 && (Qn - Mq) > 0) {
            float sv = simq[q];
            float sumneg = sq_all[sct] - sq_pos[sct];
            sq_num = sv - __logf(__expf(sv) + sumneg);
            sq_cnt = 1.f;
        }
        fred[wid][0] = qs_num; fred[wid][1] = qs_cnt;
        fred[wid][2] = sq_num; fred[wid][3] = sq_cnt;
    }
    __syncthreads();
    if (tid < 4) {
        float v = fred[0][tid] + fred[1][tid] + fred[2][tid] + fred[3][tid];
        bpart[(size_t)blockIdx.x * 4 + tid] = v;
    }
}

__global__ void combine2(const float* __restrict__ bpart, int nblk, float* __restrict__ out) {
    __shared__ float r2[4][4];
    const int tid = threadIdx.x, lane = tid & 63, wid = tid >> 6;
    float v[4] = {0.f, 0.f, 0.f, 0.f};
    for (int i = tid; i < nblk; i += 256) {
        #pragma unroll
        for (int c2 = 0; c2 < 4; ++c2) v[c2] += bpart[(size_t)i * 4 + c2];
    }
    #pragma unroll
    for (int m = 1; m < 64; m <<= 1)
        #pragma unroll
        for (int c2 = 0; c2 < 4; ++c2) v[c2] += __shfl_xor(v[c2], m);
    if (lane == 0) {
        #pragma unroll
        for (int c2 = 0; c2 < 4; ++c2) r2[wid][c2] = v[c2];
    }
    __syncthreads();
    if (tid == 0) {
        float qs_num = r2[0][0] + r2[1][0] + r2[2][0] + r2[3][0];
        float qs_cnt = r2[0][1] + r2[1][1] + r2[2][1] + r2[3][1];
        float sq_num = r2[0][2] + r2[1][2] + r2[2][2] + r2[3][2];
        float sq_cnt = r2[0][3] + r2[1][3] + r2[2][3] + r2[3][3];
        float qs = qs_cnt > 0.f ? -qs_num / qs_cnt : 0.f;
        float sq = sq_cnt > 0.f ? -sq_num / sq_cnt : 0.f;
        out[0] = qs + sq;
    }
}

extern "C" void kernel_launch(void* const* d_in, const int* in_sizes, int n_in,
                              void* d_out, int out_size, void* d_ws, size_t ws_size,
                              hipStream_t stream) {
    const float* sec = (const float*)d_in[1];
    const float* que = (const float*)d_in[2];
    const float* sen = (const float*)d_in[3];
    const int* pidq = (const int*)d_in[4];
    const int* sidx = (const int*)d_in[5];
    const int* pidn = (const int*)d_in[6];
    const int* npp = (const int*)d_in[7];
    const int S = in_sizes[1] / D;
    const int Q = in_sizes[2] / D;
    const int N = in_sizes[3] / D;
    const int NB = N / 128;
    const int FBLK = Q / 4;

    char* p = (char*)d_ws;
    unsigned char* queb = (unsigned char*)p; p += (size_t)Q * D;
    unsigned char* senb = (unsigned char*)p; p += (size_t)N * D;
    unsigned char* secb = (unsigned char*)p; p += (size_t)S * D;
    p = (char*)(((uintptr_t)p + 255) & ~(uintptr_t)255);
    float* simq = (float*)p; p += (size_t)Q * 4;
    float* pos_s = (float*)p; p += (size_t)Q * CAP * 4;
    float* partial = (float*)p; p += (size_t)NB * Q * 4;
    float* bpart = (float*)p; p += (size_t)FBLK * 4 * 4;
    char* z0 = p;
    int* cnt = (int*)p; p += (size_t)Q * 4;
    float* sq_all = (float*)p; p += (size_t)S * 4;
    float* sq_pos = (float*)p; p += (size_t)S * 4;
    int* sq_m = (int*)p; p += (size_t)S * 4;
    size_t zbytes = (size_t)(p - z0);

    hipMemsetAsync(z0, 0, zbytes, stream);
    norm_all<<<(Q + N + S + 3) / 4, 256, 0, stream>>>(que, sen, sec, queb, senb, secb, Q, N, S);
    qs_sq<<<Q / 128 + (Q / 128) * NB, 256, 0, stream>>>(queb, senb, secb, pidq, pidn, sidx, Q,
                                                        partial, cnt, pos_s,
                                                        sq_all, sq_pos, sq_m, simq);
    finish<<<FBLK, 256, 0, stream>>>(partial, NB, cnt, pos_s, sidx, simq,
                                     sq_all, sq_pos, sq_m, npp, Q, N, bpart);
    combine2<<<1, 256, 0, stream>>>(bpart, FBLK, (float*)d_out);
}

// Round 19
// 86.200 us; speedup vs baseline: 3.2796x; 3.2796x over previous
//
#include <hip/hip_runtime.h>
#include <hip/hip_bf16.h>
#include <math.h>

#define D 256
#define INV_TAU 20.0f
#define CAP 64
#define PBUF 128
// fp8 inputs scaled by 16: acc = 256*sim. s = acc*INV_TAU/256.
#define ACC2S (INV_TAU / 256.0f)
#define K2F (ACC2S * 1.4426950408889634f)

typedef __attribute__((ext_vector_type(4))) float f32x4;

#define GLOAD16(gp, lp) \
    __builtin_amdgcn_global_load_lds((const __attribute__((address_space(1))) void*)(gp), \
                                     (__attribute__((address_space(3))) void*)(lp), 16, 0, 0)

// Wave per row: L2-normalize a 256-dim f32 row, scale by 16, emit fp8 e4m3 in
// PERMUTED layout: each 64B K-block stores 8B granules in order [0,4,1,5,2,6,3,7],
// so 16B position g holds lane-g's MFMA operands for the block's (kk-even, kk-odd)
// pair — one ds_read_b128 serves two K=32 MFMA steps (R16-verified, absmax 0.0).
__global__ void norm_all(const float* __restrict__ que, const float* __restrict__ sen,
                         const float* __restrict__ sec,
                         unsigned char* __restrict__ queb, unsigned char* __restrict__ senb,
                         unsigned char* __restrict__ secb, int Q, int N, int S) {
    int r = blockIdx.x * 4 + (threadIdx.x >> 6);
    int lane = threadIdx.x & 63;
    if (r >= Q + N + S) return;
    const float* src; unsigned char* dst; int row;
    if (r < Q) { src = que; dst = queb; row = r; }
    else if (r < Q + N) { src = sen; dst = senb; row = r - Q; }
    else { src = sec; dst = secb; row = r - Q - N; }
    const float4* p = (const float4*)(src + (size_t)row * D);
    float4 v = p[lane];
    float ss = v.x * v.x + v.y * v.y + v.z * v.z + v.w * v.w;
    #pragma unroll
    for (int m = 1; m < 64; m <<= 1) ss += __shfl_xor(ss, m);
    float s = rsqrtf(ss) * 16.0f;
    int pk = __builtin_amdgcn_cvt_pk_fp8_f32(v.x * s, v.y * s, 0, false);
    pk = __builtin_amdgcn_cvt_pk_fp8_f32(v.z * s, v.w * s, pk, true);
    // lane covers granule (lane>>1), half (lane&1); block = lane>>4, wg = (lane>>1)&7.
    int wg = (lane >> 1) & 7;
    int pos = (wg < 4) ? (2 * wg) : (2 * (wg - 4) + 1);
    int byte = ((lane >> 4) << 6) + (pos << 3) + ((lane & 1) << 2);
    *(int*)(dst + (size_t)row * D + byte) = pk;
}

// Mega kernel, 1-D grid = 32 SQ blocks + 4096 QS blocks, 256 threads.
// QS: fp8 128x128 tile, BK=64 DOUBLE-BUFFERED with counted vmcnt (R8 schedule):
// STAGE(next buf) -> vmcnt(4) (prev tile landed, next in flight) -> barrier ->
// 8 ds_read_b128 + 32 MFMA -> barrier. Chunk swizzle c ^= (row>>1)&3 on SOURCE +
// READ, LDS linear (rule #21); permuted-64B fragment = one b128 per row-pair of
// kk-steps (R16's measured-0-conflict pattern). launch_bounds(256,4): VGPR 64, no spill.
__global__ __launch_bounds__(256, 4)
void qs_sq(const unsigned char* __restrict__ queb, const unsigned char* __restrict__ senb,
           const unsigned char* __restrict__ secb,
           const int* __restrict__ pidq, const int* __restrict__ pidn,
           const int* __restrict__ sidx, int Q,
           float* __restrict__ partial, int* __restrict__ cnt, float* __restrict__ pos_s,
           float* __restrict__ sq_all, float* __restrict__ sq_pos, int* __restrict__ sq_m,
           float* __restrict__ simq) {
    __shared__ unsigned char As[2][128 * 64];
    __shared__ unsigned char Bs[2][128 * 64];
    __shared__ int pqs[128];
    __shared__ int pns[128];
    __shared__ float sums[2][128];
    __shared__ int lcnt;
    __shared__ int lq[PBUF];
    __shared__ float lsv[PBUF];

    const int tid = threadIdx.x;
    const int lane = tid & 63;
    const int cl = lane & 15;
    const int g = lane >> 4;
    const int wid = tid >> 6;
    const int bid = blockIdx.x;
    const int nsq = Q >> 7;   // 32 SQ blocks

    if (bid < nsq) {
        // ---------------- SQ path: 64 sections x 128 questions (fp8, permuted) ----------------
        const int q0 = bid * 128;
        const int qw = q0 + wid * 32;
        f32x4 acc[4][2];
        #pragma unroll
        for (int si = 0; si < 4; ++si)
            #pragma unroll
            for (int qi = 0; qi < 2; ++qi)
                acc[si][qi] = (f32x4){0.f, 0.f, 0.f, 0.f};
        const unsigned char* abase = secb + (size_t)cl * D + g * 16;
        const unsigned char* bbase = queb + (size_t)(qw + cl) * D + g * 16;
        #pragma unroll
        for (int b = 0; b < 4; ++b) {
            const int k0 = b * 64;
            long2 af[4], bq[2];
            #pragma unroll
            for (int si = 0; si < 4; ++si)
                af[si] = *(const long2*)(abase + (size_t)si * 16 * D + k0);
            #pragma unroll
            for (int qi = 0; qi < 2; ++qi)
                bq[qi] = *(const long2*)(bbase + (size_t)qi * 16 * D + k0);
            #pragma unroll
            for (int si = 0; si < 4; ++si)
                #pragma unroll
                for (int qi = 0; qi < 2; ++qi) {
                    acc[si][qi] = __builtin_amdgcn_mfma_f32_16x16x32_fp8_fp8(af[si].x, bq[qi].x, acc[si][qi], 0, 0, 0);
                    acc[si][qi] = __builtin_amdgcn_mfma_f32_16x16x32_fp8_fp8(af[si].y, bq[qi].y, acc[si][qi], 0, 0, 0);
                }
        }
        int sidxv[2];
        sidxv[0] = sidx[qw + cl];
        sidxv[1] = sidx[qw + 16 + cl];
        #pragma unroll
        for (int si = 0; si < 4; ++si) {
            float pa[4] = {0.f, 0.f, 0.f, 0.f};
            #pragma unroll
            for (int qi = 0; qi < 2; ++qi) {
                #pragma unroll
                for (int j = 0; j < 4; ++j) {
                    int srow = si * 16 + g * 4 + j;
                    float sv = acc[si][qi][j] * ACC2S;
                    float e = __expf(sv);
                    pa[j] += e;
                    if (sidxv[qi] == srow) {
                        int q = qw + qi * 16 + cl;
                        simq[q] = sv;
                        atomicAdd(&sq_pos[srow], e);
                        atomicAdd(&sq_m[srow], 1);
                    }
                }
            }
            #pragma unroll
            for (int j = 0; j < 4; ++j) {
                float a = pa[j];
                #pragma unroll
                for (int msk = 1; msk < 16; msk <<= 1) a += __shfl_xor(a, msk);
                if (cl == 0) atomicAdd(&sq_all[si * 16 + g * 4 + j], a);
            }
        }
        return;
    }

    // ---------------- QS path ----------------
    const int qbid = bid - nsq;
    const int qt = qbid & 31;       // 32 consecutive blocks share the same n-tile
    const int nt = qbid >> 5;       // 128 n-tiles
    const int wr = wid >> 1, wc = wid & 1;
    const int q0 = qt * 128;
    const int n0 = nt * 128;

    if (tid < 128) pqs[tid] = pidq[q0 + tid];
    else           pns[tid - 128] = pidn[n0 + tid - 128];
    if (tid == 0) lcnt = 0;
    __syncthreads();   // pid visible + vmcnt drained before counted waits

    // Staging: per K-step stage one 64B block: 128 rows x 4 chunks = 512 chunks
    // per matrix; thread covers cid = {tid, 256+tid}: row = cid>>2, c = cid&3.
    // Source chunk = c ^ ((row>>1)&3), LDS dest linear in cid.
    const int r0s = tid >> 2;             // rows 0..63
    const int c0s = tid & 3;
    const unsigned char* qa0 = queb + (size_t)(q0 + r0s) * D + ((c0s ^ ((r0s >> 1) & 3)) << 4);
    const unsigned char* qa1 = queb + (size_t)(q0 + 64 + r0s) * D + ((c0s ^ (((r0s + 64) >> 1) & 3)) << 4);
    const unsigned char* sb0 = senb + (size_t)(n0 + r0s) * D + ((c0s ^ ((r0s >> 1) & 3)) << 4);
    const unsigned char* sb1 = senb + (size_t)(n0 + 64 + r0s) * D + ((c0s ^ (((r0s + 64) >> 1) & 3)) << 4);
    const int ld0 = wid * 1024;           // byte base, chunks 0..255
    const int ld1 = 4096 + wid * 1024;    // chunks 256..511

#define STAGE(buf, k0) do { \
    GLOAD16(qa0 + (k0), &As[buf][ld0]); \
    GLOAD16(qa1 + (k0), &As[buf][ld1]); \
    GLOAD16(sb0 + (k0), &Bs[buf][ld0]); \
    GLOAD16(sb1 + (k0), &Bs[buf][ld1]); \
} while (0)

    f32x4 acc[4][4];
    #pragma unroll
    for (int m = 0; m < 4; ++m)
        #pragma unroll
        for (int n = 0; n < 4; ++n)
            acc[m][n] = (f32x4){0.f, 0.f, 0.f, 0.f};

    // Fragment byte offsets: want global chunk (r, g); stored chunk = g ^ ((r>>1)&3),
    // and (r>>1)&3 == (cl>>1)&3 for all fragment rows (bases are multiples of 16).
    // One b128 per (frag row): lo 8B = kk-even operand, hi 8B = kk-odd operand.
    const int fsw = (g ^ ((cl >> 1) & 3)) << 4;
    int offA[4], offB[4];
    #pragma unroll
    for (int m = 0; m < 4; ++m) offA[m] = (wr * 64 + m * 16 + cl) * 64 + fsw;
    #pragma unroll
    for (int n = 0; n < 4; ++n) offB[n] = (wc * 64 + n * 16 + cl) * 64 + fsw;

    STAGE(0, 0);
    #pragma unroll
    for (int ks = 0; ks < 4; ++ks) {
        const int cur = ks & 1;
        if (ks < 3) {
            STAGE(cur ^ 1, (ks + 1) * 64);
            asm volatile("s_waitcnt vmcnt(4)" ::: "memory");
        } else {
            asm volatile("s_waitcnt vmcnt(0)" ::: "memory");
        }
        __builtin_amdgcn_s_barrier();
        long2 af[4], bg[4];
        #pragma unroll
        for (int m = 0; m < 4; ++m) af[m] = *(const long2*)&As[cur][offA[m]];
        #pragma unroll
        for (int n = 0; n < 4; ++n) bg[n] = *(const long2*)&Bs[cur][offB[n]];
        #pragma unroll
        for (int m = 0; m < 4; ++m)
            #pragma unroll
            for (int n = 0; n < 4; ++n)
                acc[m][n] = __builtin_amdgcn_mfma_f32_16x16x32_fp8_fp8(af[m].x, bg[n].x, acc[m][n], 0, 0, 0);
        #pragma unroll
        for (int m = 0; m < 4; ++m)
            #pragma unroll
            for (int n = 0; n < 4; ++n)
                acc[m][n] = __builtin_amdgcn_mfma_f32_16x16x32_fp8_fp8(af[m].y, bg[n].y, acc[m][n], 0, 0, 0);
        if (ks < 3) __builtin_amdgcn_s_barrier();
    }
#undef STAGE

    // Epilogue: exp2 + per-row sums (block-local) + LDS positive capture.
    #pragma unroll
    for (int m = 0; m < 4; ++m) {
        float se[4] = {0.f, 0.f, 0.f, 0.f};
        int pqr[4];
        #pragma unroll
        for (int j = 0; j < 4; ++j) pqr[j] = pqs[wr * 64 + m * 16 + g * 4 + j];
        #pragma unroll
        for (int n = 0; n < 4; ++n) {
            const int pcol = pns[wc * 64 + n * 16 + cl];
            #pragma unroll
            for (int j = 0; j < 4; ++j) {
                float e = __builtin_amdgcn_exp2f(acc[m][n][j] * K2F);
                se[j] += e;
                if (pqr[j] == pcol) {
                    int li = atomicAdd(&lcnt, 1);
                    if (li < PBUF) {
                        lq[li] = q0 + wr * 64 + m * 16 + g * 4 + j;
                        lsv[li] = acc[m][n][j] * ACC2S;
                    }
                }
            }
        }
        #pragma unroll
        for (int j = 0; j < 4; ++j) {
            float a = se[j];
            #pragma unroll
            for (int msk = 1; msk < 16; msk <<= 1) a += __shfl_xor(a, msk);
            if (cl == 0) sums[wc][wr * 64 + m * 16 + g * 4 + j] = a;
        }
    }
    __syncthreads();
    if (tid < 128)
        partial[(size_t)nt * Q + q0 + tid] = sums[0][tid] + sums[1][tid];
    int nc = lcnt < PBUF ? lcnt : PBUF;
    for (int i = tid; i < nc; i += 256) {
        int q = lq[i];
        int idx = atomicAdd(&cnt[q], 1);
        if (idx < CAP) pos_s[(size_t)q * CAP + idx] = lsv[i];
    }
}

// Finish: wave per question. Reduces row partials, computes g + QS terms + SQ term.
__global__ __launch_bounds__(256)
void finish(const float* __restrict__ partial, int NSLICE,
            const int* __restrict__ cnt, const float* __restrict__ pos_s,
            const int* __restrict__ sidx, const float* __restrict__ simq,
            const float* __restrict__ sq_all, const float* __restrict__ sq_pos,
            const int* __restrict__ sq_m,
            const int* __restrict__ npp, int Qn, int Ntot,
            float* __restrict__ bpart) {
    __shared__ float fred[4][4];
    const int tid = threadIdx.x, lane = tid & 63, wid = tid >> 6;
    const int q = blockIdx.x * 4 + wid;

    float Sa = 0.f;
    for (int nb = lane; nb < NSLICE; nb += 64) Sa += partial[(size_t)nb * Qn + q];
    #pragma unroll
    for (int m = 1; m < 64; m <<= 1) Sa += __shfl_xor(Sa, m);

    int M = cnt[q];
    int mc = M < CAP ? M : CAP;
    float s = 0.f, e = 0.f;
    if (lane < mc) { s = pos_s[(size_t)q * CAP + lane]; e = __expf(s); }
    float Sp = e;
    #pragma unroll
    for (int m = 1; m < 64; m <<= 1) Sp += __shfl_xor(Sp, m);

    int Nn = Ntot - M;
    int P = npp[0];
    float eta_p = 1.0f / (float)(P > 1 ? P : 1);
    float eta_m = 1.0f - eta_p;
    float Mf = (float)(M > 1 ? M : 1);
    float Nnf = (float)(Nn > 1 ? Nn : 1);
    float gg = fmaxf(((Sa - Sp) / Nnf - eta_p * Sp / Mf) / eta_m, __expf(-INV_TAU));
    float c = (float)Nn * gg;

    float contrib = (lane < mc) ? (s - __logf(e + c)) : 0.f;
    #pragma unroll
    for (int m = 1; m < 64; m <<= 1) contrib += __shfl_xor(contrib, m);

    if (lane == 0) {
        float qs_num = 0.f, qs_cnt = 0.f, sq_num = 0.f, sq_cnt = 0.f;
        if (M > 0 && Nn > 0) { qs_num = contrib; qs_cnt = (float)M; }
        int sct = sidx[q];
        int Mq = sq_m[sct];
        if (Mq > 0 && (Qn - Mq) > 0) {
            float sv = simq[q];
            float sumneg = sq_all[sct] - sq_pos[sct];
            sq_num = sv - __logf(__expf(sv) + sumneg);
            sq_cnt = 1.f;
        }
        fred[wid][0] = qs_num; fred[wid][1] = qs_cnt;
        fred[wid][2] = sq_num; fred[wid][3] = sq_cnt;
    }
    __syncthreads();
    if (tid < 4) {
        float v = fred[0][tid] + fred[1][tid] + fred[2][tid] + fred[3][tid];
        bpart[(size_t)blockIdx.x * 4 + tid] = v;
    }
}

__global__ void combine2(const float* __restrict__ bpart, int nblk, float* __restrict__ out) {
    __shared__ float r2[4][4];
    const int tid = threadIdx.x, lane = tid & 63, wid = tid >> 6;
    float v[4] = {0.f, 0.f, 0.f, 0.f};
    for (int i = tid; i < nblk; i += 256) {
        #pragma unroll
        for (int c2 = 0; c2 < 4; ++c2) v[c2] += bpart[(size_t)i * 4 + c2];
    }
    #pragma unroll
    for (int m = 1; m < 64; m <<= 1)
        #pragma unroll
        for (int c2 = 0; c2 < 4; ++c2) v[c2] += __shfl_xor(v[c2], m);
    if (lane == 0) {
        #pragma unroll
        for (int c2 = 0; c2 < 4; ++c2) r2[wid][c2] = v[c2];
    }
    __syncthreads();
    if (tid == 0) {
        float qs_num = r2[0][0] + r2[1][0] + r2[2][0] + r2[3][0];
        float qs_cnt = r2[0][1] + r2[1][1] + r2[2][1] + r2[3][1];
        float sq_num = r2[0][2] + r2[1][2] + r2[2][2] + r2[3][2];
        float sq_cnt = r2[0][3] + r2[1][3] + r2[2][3] + r2[3][3];
        float qs = qs_cnt > 0.f ? -qs_num / qs_cnt : 0.f;
        float sq = sq_cnt > 0.f ? -sq_num / sq_cnt : 0.f;
        out[0] = qs + sq;
    }
}

extern "C" void kernel_launch(void* const* d_in, const int* in_sizes, int n_in,
                              void* d_out, int out_size, void* d_ws, size_t ws_size,
                              hipStream_t stream) {
    const float* sec = (const float*)d_in[1];
    const float* que = (const float*)d_in[2];
    const float* sen = (const float*)d_in[3];
    const int* pidq = (const int*)d_in[4];
    const int* sidx = (const int*)d_in[5];
    const int* pidn = (const int*)d_in[6];
    const int* npp = (const int*)d_in[7];
    const int S = in_sizes[1] / D;
    const int Q = in_sizes[2] / D;
    const int N = in_sizes[3] / D;
    const int NB = N / 128;
    const int FBLK = Q / 4;

    char* p = (char*)d_ws;
    unsigned char* queb = (unsigned char*)p; p += (size_t)Q * D;
    unsigned char* senb = (unsigned char*)p; p += (size_t)N * D;
    unsigned char* secb = (unsigned char*)p; p += (size_t)S * D;
    p = (char*)(((uintptr_t)p + 255) & ~(uintptr_t)255);
    float* simq = (float*)p; p += (size_t)Q * 4;
    float* pos_s = (float*)p; p += (size_t)Q * CAP * 4;
    float* partial = (float*)p; p += (size_t)NB * Q * 4;
    float* bpart = (float*)p; p += (size_t)FBLK * 4 * 4;
    char* z0 = p;
    int* cnt = (int*)p; p += (size_t)Q * 4;
    float* sq_all = (float*)p; p += (size_t)S * 4;
    float* sq_pos = (float*)p; p += (size_t)S * 4;
    int* sq_m = (int*)p; p += (size_t)S * 4;
    size_t zbytes = (size_t)(p - z0);

    hipMemsetAsync(z0, 0, zbytes, stream);
    norm_all<<<(Q + N + S + 3) / 4, 256, 0, stream>>>(que, sen, sec, queb, senb, secb, Q, N, S);
    qs_sq<<<Q / 128 + (Q / 128) * NB, 256, 0, stream>>>(queb, senb, secb, pidq, pidn, sidx, Q,
                                                        partial, cnt, pos_s,
                                                        sq_all, sq_pos, sq_m, simq);
    finish<<<FBLK, 256, 0, stream>>>(partial, NB, cnt, pos_s, sidx, simq,
                                     sq_all, sq_pos, sq_m, npp, Q, N, bpart);
    combine2<<<1, 256, 0, stream>>>(bpart, FBLK, (float*)d_out);
}